// Round 1
// baseline (2113.294 us; speedup 1.0000x reference)
//
#include <hip/hip_runtime.h>
#include <hip/hip_bf16.h>

#define VOCAB 50000
#define DD 128
#define TT 512
#define BB 512
#define HH 100
#define NCLS 4
#define NT 25            // 16-wide col tiles covering 4H=400 exactly
#define ROWS 4           // real batch rows per block (MFMA tile is 16, rest padded)
#define NBLK (BB/ROWS)   // 128 blocks
#define NTHREADS 512     // 8 waves
#define ZSTR 401         // z_lds row stride (f32) to spread banks

typedef short s16x8 __attribute__((ext_vector_type(8)));
typedef float f32x4 __attribute__((ext_vector_type(4)));

static __device__ __forceinline__ unsigned short f2b(float x) {
    __hip_bfloat16 h = __float2bfloat16(x);
    return __builtin_bit_cast(unsigned short, h);
}
static __device__ __forceinline__ float sigm(float x)  { return 1.0f / (1.0f + __expf(-x)); }
static __device__ __forceinline__ float tanhx(float x) { return 1.0f - 2.0f / (1.0f + __expf(2.0f * x)); }

// ---------------- prep: cast embedding table f32 -> bf16 ----------------
__global__ void cast_emb_k(const float* __restrict__ emb, unsigned short* __restrict__ out, int n4) {
    int i = blockIdx.x * blockDim.x + threadIdx.x;
    if (i < n4) {
        float4 v = reinterpret_cast<const float4*>(emb)[i];
        ushort4 o = make_ushort4(f2b(v.x), f2b(v.y), f2b(v.z), f2b(v.w));
        reinterpret_cast<ushort4*>(out)[i] = o;
    }
}

// ---------------- prep: bake kernel & rec_kernel into per-lane MFMA B-fragments ----------------
// frag(nt, ks), lane l, elem j  <-  M[k = ks*32 + (l>>4)*8 + j][col = nt*16 + (l&15)]
// rec_kernel K is padded 100->128 with zeros.
__global__ void build_frags_k(const float* __restrict__ kern, const float* __restrict__ rec,
                              unsigned short* __restrict__ ikf, unsigned short* __restrict__ recf) {
    int tid = blockIdx.x * blockDim.x + threadIdx.x;
    if (tid >= 2 * NT * 4 * 64) return;
    int tab  = tid / (NT * 4 * 64);
    int rem  = tid % (NT * 4 * 64);
    int lane = rem & 63;
    int fs   = rem >> 6;          // nt*4 + ks
    int ks   = fs & 3, nt = fs >> 2;
    int col   = nt * 16 + (lane & 15);
    int kbase = ks * 32 + (lane >> 4) * 8;
    unsigned short* dst = (tab ? recf : ikf) + rem * 8;
#pragma unroll
    for (int j = 0; j < 8; ++j) {
        int k = kbase + j;
        float v;
        if (tab == 0) v = kern[k * 400 + col];
        else          v = (k < HH) ? rec[k * 400 + col] : 0.0f;
        dst[j] = f2b(v);
    }
}

// ---------------- fused LSTM: persistent, block-local recurrence ----------------
__global__ __launch_bounds__(NTHREADS, 2)
void lstm_fused_k(const int* __restrict__ tokens,
                  const float* __restrict__ bias,
                  const float* __restrict__ dw,
                  const float* __restrict__ db,
                  const unsigned short* __restrict__ emb_bf,
                  const unsigned short* __restrict__ ikf_tab,
                  const unsigned short* __restrict__ recf_tab,
                  float* __restrict__ out)
{
    __shared__ __align__(16) unsigned short h_lds[16 * DD]; // bf16 h, XOR-swizzled, rows 4..15 stay 0
    __shared__ float z_lds[ROWS * ZSTR];
    __shared__ float hf_lds[ROWS * HH];                     // f32 h for epilogue

    const int tid  = threadIdx.x;
    const int lane = tid & 63;
    const int w    = tid >> 6;      // wave 0..7
    const int lo   = lane & 15;
    const int hi   = lane >> 4;
    const int b0   = blockIdx.x * ROWS;
    const int lrow = (lo < ROWS) ? lo : (ROWS - 1);         // pad rows duplicate last real row
    const int rowbase = (b0 + lrow) * TT;

    const int nt0 = (w * NT) >> 3;                          // waves get 3 or 4 of the 25 tiles
    const int cnt = (((w + 1) * NT) >> 3) - nt0;

    // constant operand fragments in registers for the whole kernel
    s16x8 ikf[4][4], rcf[4][4];
    float bv[4];
#pragma unroll
    for (int i = 0; i < 4; ++i) {
        if (i < cnt) {
            bv[i] = bias[(nt0 + i) * 16 + lo];
#pragma unroll
            for (int ks = 0; ks < 4; ++ks) {
                ikf[i][ks] = *reinterpret_cast<const s16x8*>(ikf_tab  + (((nt0 + i) * 4 + ks) * 64 + lane) * 8);
                rcf[i][ks] = *reinterpret_cast<const s16x8*>(recf_tab + (((nt0 + i) * 4 + ks) * 64 + lane) * 8);
            }
        } else bv[i] = 0.0f;
    }

    for (int idx = tid; idx < 16 * DD / 2; idx += NTHREADS)
        reinterpret_cast<unsigned int*>(h_lds)[idx] = 0u;

    const int g_on  = (tid < ROWS * HH);
    const int g_row = tid / HH;
    const int g_j   = tid - g_row * HH;
    float cst = 0.0f;

    // token / x-fragment prefetch pipeline (x for step t loaded during step t-1)
    int tk0 = tokens[rowbase + 0];
    int tk1 = tokens[rowbase + 1];
    s16x8 xf[4];
#pragma unroll
    for (int ks = 0; ks < 4; ++ks)
        xf[ks] = *reinterpret_cast<const s16x8*>(emb_bf + (long)tk0 * DD + ks * 32 + hi * 8);

    __syncthreads();

    for (int t = 0; t < TT; ++t) {
        f32x4 acc[4];
#pragma unroll
        for (int i = 0; i < 4; ++i) { acc[i][0] = bv[i]; acc[i][1] = bv[i]; acc[i][2] = bv[i]; acc[i][3] = bv[i]; }

        // z += x @ kernel   (x fragments prefetched last step)
#pragma unroll
        for (int ks = 0; ks < 4; ++ks)
#pragma unroll
            for (int i = 0; i < 4; ++i)
                if (i < cnt) acc[i] = __builtin_amdgcn_mfma_f32_16x16x32_bf16(xf[ks], ikf[i][ks], acc[i], 0, 0, 0);

        // prefetch next step's token + x fragments (hidden under rec MFMA + gates)
        int tk2 = tokens[rowbase + ((t + 2 < TT) ? (t + 2) : (TT - 1))];
#pragma unroll
        for (int ks = 0; ks < 4; ++ks)
            xf[ks] = *reinterpret_cast<const s16x8*>(emb_bf + (long)tk1 * DD + ks * 32 + hi * 8);

        // h fragments from swizzled LDS (conflict-free ds_read_b128)
        s16x8 hA[4];
#pragma unroll
        for (int ks = 0; ks < 4; ++ks) {
            int off = (lo * 256 + ks * 64 + hi * 16) ^ ((lo & 7) << 4);
            hA[ks] = *reinterpret_cast<const s16x8*>(reinterpret_cast<const char*>(h_lds) + off);
        }

        // z += h @ rec_kernel
#pragma unroll
        for (int ks = 0; ks < 4; ++ks)
#pragma unroll
            for (int i = 0; i < 4; ++i)
                if (i < cnt) acc[i] = __builtin_amdgcn_mfma_f32_16x16x32_bf16(hA[ks], rcf[i][ks], acc[i], 0, 0, 0);

        // write real z rows (C layout: row=(lane>>4)*4+r, col=lane&15 -> rows 0..3 live in hi==0 lanes)
        if (hi == 0) {
#pragma unroll
            for (int i = 0; i < 4; ++i)
                if (i < cnt) {
#pragma unroll
                    for (int r = 0; r < 4; ++r)
                        z_lds[r * ZSTR + (nt0 + i) * 16 + lo] = acc[i][r];
                }
        }
        __syncthreads();

        // gates: one (row, j) element per thread
        if (g_on) {
            float zi = z_lds[g_row * ZSTR + g_j];
            float zf = z_lds[g_row * ZSTR + HH + g_j];
            float zg = z_lds[g_row * ZSTR + 2 * HH + g_j];
            float zo = z_lds[g_row * ZSTR + 3 * HH + g_j];
            float ig = sigm(zi), fg = sigm(zf), gg = tanhx(zg), og = sigm(zo);
            cst = fg * cst + ig * gg;
            float hh = og * tanhx(cst);
            int off = (g_row * 256 + g_j * 2) ^ ((g_row & 7) << 4);
            *reinterpret_cast<unsigned short*>(reinterpret_cast<char*>(h_lds) + off) = f2b(hh);
            if (t == TT - 1) hf_lds[g_row * HH + g_j] = hh;
        }
        tk1 = tk2;
        __syncthreads();
    }

    // epilogue: logits + softmax for this block's 4 rows (f32 h)
    if (tid < ROWS * NCLS) {
        int r = tid >> 2, cc = tid & 3;
        float s = db[cc];
#pragma unroll 4
        for (int k = 0; k < HH; ++k)
            s += hf_lds[r * HH + k] * dw[k * NCLS + cc];
        float m = s;
        m = fmaxf(m, __shfl_xor(m, 1));
        m = fmaxf(m, __shfl_xor(m, 2));
        float e = __expf(s - m);
        float den = e;
        den += __shfl_xor(den, 1);
        den += __shfl_xor(den, 2);
        out[(b0 + r) * NCLS + cc] = e / den;
    }
}

extern "C" void kernel_launch(void* const* d_in, const int* in_sizes, int n_in,
                              void* d_out, int out_size, void* d_ws, size_t ws_size,
                              hipStream_t stream) {
    const int*   tokens = (const int*)d_in[0];
    const float* emb    = (const float*)d_in[1];
    const float* kern   = (const float*)d_in[2];
    const float* rec    = (const float*)d_in[3];
    const float* bias   = (const float*)d_in[4];
    const float* dw     = (const float*)d_in[5];
    const float* db     = (const float*)d_in[6];
    float* out = (float*)d_out;

    // workspace layout (all 16B aligned): emb_bf16 | ik frag table | rec frag table  (~12.6 MB)
    unsigned short* emb_bf = (unsigned short*)d_ws;
    unsigned short* ikf    = emb_bf + (size_t)VOCAB * DD;        // +12,800,000 B
    unsigned short* recf   = ikf + NT * 4 * 64 * 8;              // +102,400 B

    int n4 = VOCAB * DD / 4;
    cast_emb_k<<<(n4 + 255) / 256, 256, 0, stream>>>(emb, emb_bf, n4);
    build_frags_k<<<(2 * NT * 4 * 64 + 255) / 256, 256, 0, stream>>>(kern, rec, ikf, recf);
    lstm_fused_k<<<NBLK, NTHREADS, 0, stream>>>(tokens, bias, dw, db, emb_bf, ikf, recf, out);
}

// Round 2
// 801.682 us; speedup vs baseline: 2.6361x; 2.6361x over previous
//
#include <hip/hip_runtime.h>
#include <hip/hip_bf16.h>

#define VOCAB 50000
#define DD 128
#define TT 512
#define BB 512
#define HH 100
#define NCLS 4
#define NT 25            // 16-wide col tiles covering 4H=400 exactly
#define ROWS 4           // real batch rows per block in recurrent kernel
#define NBLK (BB/ROWS)   // 128 blocks
#define NTHREADS 512     // 8 waves
#define ZSTR 401         // z_lds row stride (f32)
#define GBLK 2048        // xz GEMM blocks
#define SPB ((TT*BB/16)/GBLK)   // 16-row strips per GEMM block = 8

typedef short s16x8 __attribute__((ext_vector_type(8)));
typedef float f32x4 __attribute__((ext_vector_type(4)));

static __device__ __forceinline__ unsigned short f2b(float x) {
    __hip_bfloat16 h = __float2bfloat16(x);
    return __builtin_bit_cast(unsigned short, h);
}
static __device__ __forceinline__ float b2f(unsigned short u) {
    unsigned int v = (unsigned int)u << 16;
    return __builtin_bit_cast(float, v);
}
static __device__ __forceinline__ float sigm(float x)  { return 1.0f / (1.0f + __expf(-x)); }
static __device__ __forceinline__ float tanhx(float x) { return 1.0f - 2.0f / (1.0f + __expf(2.0f * x)); }

static __device__ __forceinline__ float xz_get(const float* p, int i)          { return p[i]; }
static __device__ __forceinline__ float xz_get(const unsigned short* p, int i) { return b2f(p[i]); }
static __device__ __forceinline__ void  xz_put(float* p, long i, float v)          { p[i] = v; }
static __device__ __forceinline__ void  xz_put(unsigned short* p, long i, float v) { p[i] = f2b(v); }

// raw barrier: waits LDS ops only, leaves global loads (vmcnt) in flight
#define BARRIER() asm volatile("s_waitcnt lgkmcnt(0)\n\ts_barrier" ::: "memory")

// ---------------- prep: cast embedding table f32 -> bf16 ----------------
__global__ void cast_emb_k(const float* __restrict__ emb, unsigned short* __restrict__ out, int n4) {
    int i = blockIdx.x * blockDim.x + threadIdx.x;
    if (i < n4) {
        float4 v = reinterpret_cast<const float4*>(emb)[i];
        ushort4 o = make_ushort4(f2b(v.x), f2b(v.y), f2b(v.z), f2b(v.w));
        reinterpret_cast<ushort4*>(out)[i] = o;
    }
}

// ---------------- prep: bake kernel & rec_kernel into per-lane MFMA B-fragments ----------------
// frag(nt, ks), lane l, elem j  <-  M[k = ks*32 + (l>>4)*8 + j][col = nt*16 + (l&15)]
__global__ void build_frags_k(const float* __restrict__ kern, const float* __restrict__ rec,
                              unsigned short* __restrict__ ikf, unsigned short* __restrict__ recf) {
    int tid = blockIdx.x * blockDim.x + threadIdx.x;
    if (tid >= 2 * NT * 4 * 64) return;
    int tab  = tid / (NT * 4 * 64);
    int rem  = tid % (NT * 4 * 64);
    int lane = rem & 63;
    int fs   = rem >> 6;
    int ks   = fs & 3, nt = fs >> 2;
    int col   = nt * 16 + (lane & 15);
    int kbase = ks * 32 + (lane >> 4) * 8;
    unsigned short* dst = (tab ? recf : ikf) + rem * 8;
#pragma unroll
    for (int j = 0; j < 8; ++j) {
        int k = kbase + j;
        float v;
        if (tab == 0) v = kern[k * 400 + col];
        else          v = (k < HH) ? rec[k * 400 + col] : 0.0f;
        dst[j] = f2b(v);
    }
}

// ---------------- bulk input-projection GEMM: xz[t*B+b][400] = emb[tok] @ kernel + bias ----------------
template<typename XZT>
__global__ __launch_bounds__(512, 2)
void xz_gemm_k(const int* __restrict__ tokens, const float* __restrict__ bias,
               const unsigned short* __restrict__ emb_bf,
               const unsigned short* __restrict__ ikf_tab,
               XZT* __restrict__ xz)
{
    const int tid = threadIdx.x, lane = tid & 63, w = tid >> 6;
    const int lo = lane & 15, hi = lane >> 4;
    const int nt0 = (w * NT) >> 3;
    const int cnt = (((w + 1) * NT) >> 3) - nt0;   // 3 or 4 tiles per wave

    s16x8 bf[4][4]; float bv[4];
#pragma unroll
    for (int i = 0; i < 4; ++i) {
        if (i < cnt) {
            bv[i] = bias[(nt0 + i) * 16 + lo];
#pragma unroll
            for (int ks = 0; ks < 4; ++ks)
                bf[i][ks] = *reinterpret_cast<const s16x8*>(ikf_tab + (((nt0 + i) * 4 + ks) * 64 + lane) * 8);
        } else bv[i] = 0.0f;
    }

    int m   = blockIdx.x * SPB * 16 + lo;                 // A-row index = t*B + b
    int tok = tokens[(m & (BB - 1)) * TT + (m >> 9)];     // tokens[b][t]
    for (int s = 0; s < SPB; ++s) {
        const int strip = blockIdx.x * SPB + s;
        s16x8 aF[4];
        long ebase = (long)tok * DD;
#pragma unroll
        for (int ks = 0; ks < 4; ++ks)
            aF[ks] = *reinterpret_cast<const s16x8*>(emb_bf + ebase + ks * 32 + hi * 8);
        m += 16;
        if (s + 1 < SPB) tok = tokens[(m & (BB - 1)) * TT + (m >> 9)];  // next-strip token prefetch

        f32x4 acc[4];
#pragma unroll
        for (int i = 0; i < 4; ++i) { acc[i][0] = bv[i]; acc[i][1] = bv[i]; acc[i][2] = bv[i]; acc[i][3] = bv[i]; }
#pragma unroll
        for (int ks = 0; ks < 4; ++ks)
#pragma unroll
            for (int i = 0; i < 4; ++i)
                if (i < cnt) acc[i] = __builtin_amdgcn_mfma_f32_16x16x32_bf16(aF[ks], bf[i][ks], acc[i], 0, 0, 0);
#pragma unroll
        for (int i = 0; i < 4; ++i) if (i < cnt) {
#pragma unroll
            for (int r = 0; r < 4; ++r) {
                int row = strip * 16 + hi * 4 + r;         // C layout: row=(lane>>4)*4+r
                int col = (nt0 + i) * 16 + lo;             //           col=lane&15
                xz_put(xz, (long)row * 400 + col, acc[i][r]);
            }
        }
    }
}

// ---------------- recurrent kernel: block-local 512-step recurrence ----------------
template<typename XZT>
__global__ __launch_bounds__(NTHREADS, 2)
void lstm_rec_k(const float* __restrict__ dw, const float* __restrict__ db,
                const unsigned short* __restrict__ recf_tab,
                const XZT* __restrict__ xz, float* __restrict__ out)
{
    __shared__ __align__(16) unsigned short h_lds[16 * DD];  // bf16 h, XOR-swizzled
    __shared__ float z_lds[ROWS * ZSTR];                     // rec-part only
    __shared__ float hf_lds[ROWS * HH];
    __shared__ float dw_lds[HH * NCLS];

    const int tid = threadIdx.x, lane = tid & 63, w = tid >> 6;
    const int lo = lane & 15, hi = lane >> 4;
    const int b0 = blockIdx.x * ROWS;
    const int nt0 = (w * NT) >> 3;
    const int cnt = (((w + 1) * NT) >> 3) - nt0;

    // only rec-kernel fragments live in registers now (<= 64 VGPR)
    s16x8 rcf[4][4];
#pragma unroll
    for (int i = 0; i < 4; ++i) if (i < cnt)
#pragma unroll
        for (int ks = 0; ks < 4; ++ks)
            rcf[i][ks] = *reinterpret_cast<const s16x8*>(recf_tab + (((nt0 + i) * 4 + ks) * 64 + lane) * 8);

    for (int idx = tid; idx < 16 * DD / 2; idx += NTHREADS)
        reinterpret_cast<unsigned int*>(h_lds)[idx] = 0u;
    if (tid < HH * NCLS) dw_lds[tid] = dw[tid];

    const bool g_on = tid < ROWS * HH;
    const int g_row = tid / HH, g_j = tid - g_row * HH;
    float cst = 0.0f;

    int hoff[4];
#pragma unroll
    for (int ks = 0; ks < 4; ++ks) hoff[ks] = (lo * 256 + ks * 64 + hi * 16) ^ ((lo & 7) << 4);

    // 2-deep xz register prefetch (static double buffer via t-loop unroll by 2)
    float xzA[4], xzB[4];
    if (g_on) {
        int base0 = (0 * BB + b0 + g_row) * 400 + g_j;
        int base1 = (1 * BB + b0 + g_row) * 400 + g_j;
#pragma unroll
        for (int c = 0; c < 4; ++c) { xzA[c] = xz_get(xz, base0 + c * HH); xzB[c] = xz_get(xz, base1 + c * HH); }
    }
    __syncthreads();

    auto step = [&](int t, float (&buf)[4]) {
        // issue xz(t+2) prefetch first: in flight across ~2 steps, never drained (raw barriers)
        float nb[4];
        if (g_on) {
            int t2 = (t + 2 < TT) ? t + 2 : TT - 1;
            int nbase = (t2 * BB + b0 + g_row) * 400 + g_j;
#pragma unroll
            for (int c = 0; c < 4; ++c) nb[c] = xz_get(xz, nbase + c * HH);
        }
        // phase A: rec-part GEMM on h(t-1)
        s16x8 hA[4];
#pragma unroll
        for (int ks = 0; ks < 4; ++ks)
            hA[ks] = *reinterpret_cast<const s16x8*>(reinterpret_cast<const char*>(h_lds) + hoff[ks]);
        f32x4 acc[4];
#pragma unroll
        for (int i = 0; i < 4; ++i) { acc[i][0] = 0.f; acc[i][1] = 0.f; acc[i][2] = 0.f; acc[i][3] = 0.f; }
#pragma unroll
        for (int ks = 0; ks < 4; ++ks)
#pragma unroll
            for (int i = 0; i < 4; ++i)
                if (i < cnt) acc[i] = __builtin_amdgcn_mfma_f32_16x16x32_bf16(hA[ks], rcf[i][ks], acc[i], 0, 0, 0);
        if (hi == 0) {
#pragma unroll
            for (int i = 0; i < 4; ++i) if (i < cnt)
#pragma unroll
                for (int r = 0; r < 4; ++r)
                    z_lds[r * ZSTR + (nt0 + i) * 16 + lo] = acc[i][r];
        }
        BARRIER();
        // phase B: gates (z = xz_reg + rec_lds)
        if (g_on) {
            float zi = z_lds[g_row * ZSTR + g_j]          + buf[0];
            float zf = z_lds[g_row * ZSTR + HH + g_j]     + buf[1];
            float zg = z_lds[g_row * ZSTR + 2 * HH + g_j] + buf[2];
            float zo = z_lds[g_row * ZSTR + 3 * HH + g_j] + buf[3];
            float ig = sigm(zi), fg = sigm(zf), gg = tanhx(zg), og = sigm(zo);
            cst = fg * cst + ig * gg;
            float hh = og * tanhx(cst);
            int off = (g_row * 256 + g_j * 2) ^ ((g_row & 7) << 4);
            *reinterpret_cast<unsigned short*>(reinterpret_cast<char*>(h_lds) + off) = f2b(hh);
            if (t == TT - 1) hf_lds[g_row * HH + g_j] = hh;
#pragma unroll
            for (int c = 0; c < 4; ++c) buf[c] = nb[c];
        }
        BARRIER();
    };

    for (int t = 0; t < TT; t += 2) { step(t, xzA); step(t + 1, xzB); }

    // epilogue: logits + softmax
    if (tid < ROWS * NCLS) {
        int r = tid >> 2, c = tid & 3;
        float s = db[c];
#pragma unroll 4
        for (int k = 0; k < HH; ++k)
            s += hf_lds[r * HH + k] * dw_lds[k * NCLS + c];
        float mx = s;
        mx = fmaxf(mx, __shfl_xor(mx, 1));
        mx = fmaxf(mx, __shfl_xor(mx, 2));
        float e = __expf(s - mx);
        float den = e;
        den += __shfl_xor(den, 1);
        den += __shfl_xor(den, 2);
        out[(b0 + r) * NCLS + c] = e / den;
    }
}

extern "C" void kernel_launch(void* const* d_in, const int* in_sizes, int n_in,
                              void* d_out, int out_size, void* d_ws, size_t ws_size,
                              hipStream_t stream) {
    const int*   tokens = (const int*)d_in[0];
    const float* emb    = (const float*)d_in[1];
    const float* kern   = (const float*)d_in[2];
    const float* rec    = (const float*)d_in[3];
    const float* bias   = (const float*)d_in[4];
    const float* dw     = (const float*)d_in[5];
    const float* db     = (const float*)d_in[6];
    float* out = (float*)d_out;

    // ws layout: emb_bf16 (12.8MB) | ikf (100KB) | recf (100KB) | xz
    unsigned short* emb_bf = (unsigned short*)d_ws;
    unsigned short* ikf    = emb_bf + (size_t)VOCAB * DD;
    unsigned short* recf   = ikf + NT * 4 * 64 * 8;
    char*           xz_raw = (char*)(recf + NT * 4 * 64 * 8);
    const size_t head      = (size_t)VOCAB * DD * 2 + 2 * (size_t)NT * 4 * 64 * 8 * 2;
    const size_t need_f32  = head + (size_t)TT * BB * 400 * 4;

    int n4 = VOCAB * DD / 4;
    cast_emb_k<<<(n4 + 255) / 256, 256, 0, stream>>>(emb, emb_bf, n4);
    build_frags_k<<<(2 * NT * 4 * 64 + 255) / 256, 256, 0, stream>>>(kern, rec, ikf, recf);

    if (ws_size >= need_f32) {
        float* xz = (float*)xz_raw;
        xz_gemm_k<float><<<GBLK, 512, 0, stream>>>(tokens, bias, emb_bf, ikf, xz);
        lstm_rec_k<float><<<NBLK, NTHREADS, 0, stream>>>(dw, db, recf, xz, out);
    } else {
        unsigned short* xz = (unsigned short*)xz_raw;
        xz_gemm_k<unsigned short><<<GBLK, 512, 0, stream>>>(tokens, bias, emb_bf, ikf, xz);
        lstm_rec_k<unsigned short><<<NBLK, NTHREADS, 0, stream>>>(dw, db, recf, xz, out);
    }
}

// Round 3
// 656.303 us; speedup vs baseline: 3.2200x; 1.2215x over previous
//
#include <hip/hip_runtime.h>
#include <hip/hip_bf16.h>

#define VOCAB 50000
#define DD 128
#define TT 512
#define BB 512
#define HH 100
#define NCLS 4
#define NT 25            // 16-wide permuted col tiles covering 4H=400 exactly
#define ROWS 4           // real batch rows per block
#define NBLK (BB/ROWS)   // 128 blocks
#define NTHREADS 512     // 8 waves
#define ZS 400           // z_lds row stride (f32, float4-aligned)

typedef short s16x8 __attribute__((ext_vector_type(8)));
typedef float f32x4 __attribute__((ext_vector_type(4)));

static __device__ __forceinline__ unsigned short f2b(float x) {
    __hip_bfloat16 h = __float2bfloat16(x);
    return __builtin_bit_cast(unsigned short, h);
}
static __device__ __forceinline__ float sigm(float x)  { return __fdividef(1.0f, 1.0f + __expf(-x)); }
static __device__ __forceinline__ float tanhx(float x) { return 1.0f - __fdividef(2.0f, 1.0f + __expf(2.0f * x)); }

// raw barrier: waits LDS ops only; global loads (vmcnt) stay in flight
#define BARRIER() asm volatile("s_waitcnt lgkmcnt(0)\n\ts_barrier" ::: "memory")

// ---------------- prep: cast embedding table f32 -> bf16 ----------------
__global__ void cast_emb_k(const float* __restrict__ emb, unsigned short* __restrict__ out, int n4) {
    int i = blockIdx.x * blockDim.x + threadIdx.x;
    if (i < n4) {
        float4 v = reinterpret_cast<const float4*>(emb)[i];
        ushort4 o = make_ushort4(f2b(v.x), f2b(v.y), f2b(v.z), f2b(v.w));
        reinterpret_cast<ushort4*>(out)[i] = o;
    }
}

// ---------------- prep: bake kernel & rec_kernel into per-lane MFMA B-fragments ----------------
// PERMUTED columns: dest col c' = j*4 + gate  <->  orig col = (c'&3)*100 + (c'>>2)
// frag(nt, ks), lane l, elem j <- M[k = ks*32 + (l>>4)*8 + j][orig_col(nt*16 + (l&15))]
__global__ void build_frags_k(const float* __restrict__ kern, const float* __restrict__ rec,
                              unsigned short* __restrict__ ikf, unsigned short* __restrict__ recf) {
    int tid = blockIdx.x * blockDim.x + threadIdx.x;
    if (tid >= 2 * NT * 4 * 64) return;
    int tab  = tid / (NT * 4 * 64);
    int rem  = tid % (NT * 4 * 64);
    int lane = rem & 63;
    int fs   = rem >> 6;
    int ks   = fs & 3, nt = fs >> 2;
    int cp    = nt * 16 + (lane & 15);           // permuted col
    int oc    = (cp & 3) * 100 + (cp >> 2);      // original col
    int kbase = ks * 32 + (lane >> 4) * 8;
    unsigned short* dst = (tab ? recf : ikf) + rem * 8;
#pragma unroll
    for (int j = 0; j < 8; ++j) {
        int k = kbase + j;
        float v;
        if (tab == 0) v = kern[k * 400 + oc];
        else          v = (k < HH) ? rec[k * 400 + oc] : 0.0f;
        dst[j] = f2b(v);
    }
}

// ---------------- fused LSTM: persistent, one barrier per step ----------------
__global__ __launch_bounds__(NTHREADS, 2)
void lstm_fused2_k(const int* __restrict__ tokens,
                   const float* __restrict__ bias,
                   const float* __restrict__ dw,
                   const float* __restrict__ db,
                   const unsigned short* __restrict__ emb_bf,
                   const unsigned short* __restrict__ ikf_tab,
                   const unsigned short* __restrict__ recf_tab,
                   float* __restrict__ out)
{
    __shared__ __align__(16) unsigned short h_lds[2][16 * DD]; // bf16 h double buffer, XOR-swizzled, rows 4..15 zero
    __shared__ float z_lds[ROWS][ZS];                          // permuted z, wave-private col ranges
    __shared__ float hf_lds[ROWS * HH];
    __shared__ float dw_lds[HH * NCLS];
    __shared__ int   tok_lds[ROWS][TT];

    const int tid = threadIdx.x, lane = tid & 63, w = tid >> 6;
    const int lo = lane & 15, hi = lane >> 4;
    const int b0 = blockIdx.x * ROWS;
    const int nt0 = (w * NT) >> 3;
    const int cnt = (((w + 1) * NT) >> 3) - nt0;   // 3 or 4 tiles per wave

    // weight fragments live in registers the whole kernel (~128 VGPR)
    s16x8 ikf[4][4], rcf[4][4];
    float bv[4];
#pragma unroll
    for (int i = 0; i < 4; ++i) {
        if (i < cnt) {
            int cp = (nt0 + i) * 16 + lo;
            bv[i] = bias[(cp & 3) * 100 + (cp >> 2)];
#pragma unroll
            for (int ks = 0; ks < 4; ++ks) {
                ikf[i][ks] = *reinterpret_cast<const s16x8*>(ikf_tab  + (((nt0 + i) * 4 + ks) * 64 + lane) * 8);
                rcf[i][ks] = *reinterpret_cast<const s16x8*>(recf_tab + (((nt0 + i) * 4 + ks) * 64 + lane) * 8);
            }
        } else bv[i] = 0.0f;
    }

    for (int idx = tid; idx < 16 * DD; idx += NTHREADS)   // zero both h buffers (2*16*DD ushorts = 16*DD uints)
        reinterpret_cast<unsigned int*>(&h_lds[0][0])[idx] = 0u;
    for (int idx = tid; idx < ROWS * TT; idx += NTHREADS)
        tok_lds[idx >> 9][idx & (TT - 1)] = tokens[(b0 + (idx >> 9)) * TT + (idx & (TT - 1))];
    if (tid < HH * NCLS) dw_lds[tid] = dw[tid];

    const int  grow = hi;                 // gate row 0..3
    const int  gjl  = lo;                 // gate j-local 0..15
    const bool g_on = gjl < 4 * cnt;      // all 64 lanes active when cnt==4
    float cst = 0.0f;

    const int xrow = lo & 3;              // A rows 4..15 duplicate rows 0..3 (pad C rows unused)
    int hofA[4], hofB[4];
#pragma unroll
    for (int ks = 0; ks < 4; ++ks) {
        int o = (lo * 256 + ks * 64 + hi * 16) ^ ((lo & 7) << 4);
        hofA[ks] = o;            // read buffer parity 1 handled via pointer
        hofB[ks] = o;
    }

    // x prefetch: 2-deep alternating buffers, loads land directly in freed buffer
    s16x8 xfA[4], xfB[4];
    {
        int t0 = tokens[(b0 + xrow) * TT + 0];
        int t1 = tokens[(b0 + xrow) * TT + 1];
#pragma unroll
        for (int ks = 0; ks < 4; ++ks) {
            xfA[ks] = *reinterpret_cast<const s16x8*>(emb_bf + (long)t0 * DD + ks * 32 + hi * 8);
            xfB[ks] = *reinterpret_cast<const s16x8*>(emb_bf + (long)t1 * DD + ks * 32 + hi * 8);
        }
    }
    __syncthreads();

    auto step = [&](int t, s16x8 (&xf)[4], const int (&hof)[4],
                    const unsigned short* hrd, unsigned short* hwr) {
        // h A-fragments from swizzled LDS (issue early; latency overlaps x-MFMAs)
        s16x8 hA[4];
#pragma unroll
        for (int ks = 0; ks < 4; ++ks)
            hA[ks] = *reinterpret_cast<const s16x8*>(reinterpret_cast<const char*>(hrd) + hof[ks]);

        f32x4 acc[4];
#pragma unroll
        for (int i = 0; i < 4; ++i) { acc[i][0] = bv[i]; acc[i][1] = bv[i]; acc[i][2] = bv[i]; acc[i][3] = bv[i]; }

        // x-part MFMAs (xf loaded 2 steps ago — vmcnt wait here, ~1000cy cover)
#pragma unroll
        for (int ks = 0; ks < 4; ++ks)
#pragma unroll
            for (int i = 0; i < 4; ++i)
                if (i < cnt) acc[i] = __builtin_amdgcn_mfma_f32_16x16x32_bf16(xf[ks], ikf[i][ks], acc[i], 0, 0, 0);

        // issue x prefetch for t+2 into the just-freed buffer (no copies)
        {
            int t2 = (t + 2 < TT) ? t + 2 : TT - 1;
            int tk = tok_lds[xrow][t2];
            const unsigned short* ep = emb_bf + (long)tk * DD;
#pragma unroll
            for (int ks = 0; ks < 4; ++ks)
                xf[ks] = *reinterpret_cast<const s16x8*>(ep + ks * 32 + hi * 8);
        }

        // h-part MFMAs
#pragma unroll
        for (int ks = 0; ks < 4; ++ks)
#pragma unroll
            for (int i = 0; i < 4; ++i)
                if (i < cnt) acc[i] = __builtin_amdgcn_mfma_f32_16x16x32_bf16(hA[ks], rcf[i][ks], acc[i], 0, 0, 0);

        // z write: real rows only (hi==0 lanes), wave-private col range -> no barrier
        if (hi == 0) {
#pragma unroll
            for (int i = 0; i < 4; ++i) if (i < cnt)
#pragma unroll
                for (int r = 0; r < 4; ++r)
                    z_lds[r][(nt0 + i) * 16 + lo] = acc[i][r];
        }

        // gates: read own wave's z (float4 = i,f,g,o thanks to permutation)
        if (g_on) {
            float4 z4 = *reinterpret_cast<const float4*>(&z_lds[grow][nt0 * 16 + gjl * 4]);
            float ig = sigm(z4.x), fg = sigm(z4.y), gg = tanhx(z4.z), og = sigm(z4.w);
            cst = fg * cst + ig * gg;
            float hh = og * tanhx(cst);
            int j = nt0 * 4 + gjl;
            *reinterpret_cast<unsigned short*>(reinterpret_cast<char*>(hwr) +
                ((grow * 256 + j * 2) ^ (grow << 4))) = f2b(hh);
            if (t == TT - 1) hf_lds[grow * HH + j] = hh;
        }
        BARRIER();
    };

    for (int t = 0; t < TT; t += 2) {
        // t even: read h_{t-1} from buf1, write h_t to buf0
        step(t,     xfA, hofA, h_lds[1], h_lds[0]);
        // t odd: read buf0, write buf1
        step(t + 1, xfB, hofB, h_lds[0], h_lds[1]);
    }

    // epilogue: logits + softmax for this block's 4 rows
    if (tid < ROWS * NCLS) {
        int r = tid >> 2, c = tid & 3;
        float s = db[c];
#pragma unroll 4
        for (int k = 0; k < HH; ++k)
            s += hf_lds[r * HH + k] * dw_lds[k * NCLS + c];
        float mx = s;
        mx = fmaxf(mx, __shfl_xor(mx, 1));
        mx = fmaxf(mx, __shfl_xor(mx, 2));
        float e = __expf(s - mx);
        float den = e;
        den += __shfl_xor(den, 1);
        den += __shfl_xor(den, 2);
        out[(b0 + r) * NCLS + c] = e / den;
    }
}

extern "C" void kernel_launch(void* const* d_in, const int* in_sizes, int n_in,
                              void* d_out, int out_size, void* d_ws, size_t ws_size,
                              hipStream_t stream) {
    const int*   tokens = (const int*)d_in[0];
    const float* emb    = (const float*)d_in[1];
    const float* kern   = (const float*)d_in[2];
    const float* rec    = (const float*)d_in[3];
    const float* bias   = (const float*)d_in[4];
    const float* dw     = (const float*)d_in[5];
    const float* db     = (const float*)d_in[6];
    float* out = (float*)d_out;

    // ws layout: emb_bf16 (12.8MB) | ikf (100KB) | recf (100KB)
    unsigned short* emb_bf = (unsigned short*)d_ws;
    unsigned short* ikf    = emb_bf + (size_t)VOCAB * DD;
    unsigned short* recf   = ikf + NT * 4 * 64 * 8;

    int n4 = VOCAB * DD / 4;
    cast_emb_k<<<(n4 + 255) / 256, 256, 0, stream>>>(emb, emb_bf, n4);
    build_frags_k<<<(2 * NT * 4 * 64 + 255) / 256, 256, 0, stream>>>(kern, rec, ikf, recf);
    lstm_fused2_k<<<NBLK, NTHREADS, 0, stream>>>(tokens, bias, dw, db, emb_bf, ikf, recf, out);
}